// Round 20
// baseline (136.436 us; speedup 1.0000x reference)
//
#include <hip/hip_runtime.h>
#include <math.h>

#define NB 8
#define NS 512
#define NE 32
#define DE 256
#define DH 512
#define DA 200
#define DAP 224   // padded att dim (7 tiles of 32)
#define NJ 7

typedef __bf16 bf16x8 __attribute__((ext_vector_type(8)));
typedef float f32x16 __attribute__((ext_vector_type(16)));

#define GLOBAL_AS __attribute__((address_space(1)))
#define LDS_AS    __attribute__((address_space(3)))

__device__ __forceinline__ float tanh_fast(float x) {
    float e = __expf(x + x);
    return fmaf(-2.f, __builtin_amdgcn_rcpf(e + 1.f), 1.f);
}

// ---- stage 1: partial sums of cxt over s-chunks (512 blocks) ----
__global__ __launch_bounds__(256) void cmean_partial(const float* __restrict__ cxt,
                                                     float* __restrict__ psum) {
    const int g = blockIdx.x;       // b*64 + c
    const int b = g >> 6, c = g & 63;
    const int t = threadIdx.x;
    const float* base = cxt + ((size_t)b * NS + c * 8) * DH;
    float s0 = 0.f, s1 = 0.f;
    #pragma unroll
    for (int s = 0; s < 8; ++s) {
        s0 += base[s * DH + t];
        s1 += base[s * DH + t + 256];
    }
    psum[(size_t)g * DH + t]       = s0;
    psum[(size_t)g * DH + t + 256] = s1;
}

// ---- stage 2: reduce partials -> cmean; hatt[b][a] = cmean @ Wh (zero-padded) ----
__global__ __launch_bounds__(256) void hatt_from_psum(const float* __restrict__ psum,
                                                      const float* __restrict__ Wh,
                                                      float* __restrict__ hattw) {
    const int b = blockIdx.x;
    const int t = threadIdx.x;
    __shared__ float cm[DH];
    float s0 = 0.f, s1 = 0.f;
    for (int c = 0; c < 64; ++c) {
        s0 += psum[((size_t)b * 64 + c) * DH + t];
        s1 += psum[((size_t)b * 64 + c) * DH + t + 256];
    }
    cm[t]       = s0 * (1.f / NS);
    cm[t + 256] = s1 * (1.f / NS);
    __syncthreads();
    if (t < DAP) {
        float acc = 0.f;
        if (t < DA)
            for (int h = 0; h < DH; ++h)
                acc = fmaf(cm[h], Wh[h * DA + t], acc);
        hattw[b * DAP + t] = acc;
    }
}

// ---- stage 3: pack We into bf16 B-fragment layout (zero-padded cols) ----
__global__ __launch_bounds__(64) void wef_build(const float* __restrict__ We,
                                                __bf16* __restrict__ wef) {
    const int f = blockIdx.x;
    const int l = threadIdx.x;
    const int nj = f >> 4, kk = f & 15;
    const int n = nj * 32 + (l & 31);
    bf16x8 v;
    #pragma unroll
    for (int e = 0; e < 8; ++e) {
        int K = kk * 16 + ((l >> 5) << 2) + (e & 3) + 8 * (e >> 2);
        v[e] = (__bf16)((n < DA) ? We[K * DA + n] : 0.f);
    }
    reinterpret_cast<bf16x8*>(wef)[f * 64 + l] = v;
}

// ---- main: DMA staging x multi-block/CU decorrelation ----
// 2048 blocks x 512 thr x 2 tiles. Stage 64KB via global_load_lds (fire-and-
// forget, zero VGPR — the only staging path measured at ~6.7 TB/s on this
// chip, m97 structure), swizzled SOURCE + linear LDS dest (r17-verified).
// One barrier; B-frags register-resident (1 nj/wave, L2-hot wef read once);
// swizzled LDS gather for A-frags (4-way, 1.58x); epilogue from LDS.
// 67KB LDS + <=128 VGPR -> 2 decorrelated blocks/CU.
__global__ __launch_bounds__(512, 2) void entatt_main(const float* __restrict__ ent,
                                                      const __bf16* __restrict__ wef,
                                                      const float* __restrict__ hattw,
                                                      const float* __restrict__ Ws,
                                                      float* __restrict__ out) {
    const int t    = threadIdx.x;
    const int lane = t & 63;
    const int wid  = t >> 6;            // 0..7
    const int m    = lane & 31;
    const int hi   = lane >> 5;
    const int g    = blockIdx.x;        // 0..2047, 2 tiles each
    const int bs0  = g * 2;
    const int b    = g >> 8;            // 256 blocks per batch

    __shared__ float buf[2 * 8192];         // 2 tiles x 32KB, swizzled quads
    __shared__ float partials[2][NJ][NE];

    // ---- issue all 64KB of DMA first (fire-and-forget, no VGPR cost) ----
    // wave wid stages rows R = wid*8+j; swizzle key j = R&7; lane's 16B source
    // = row start + ((lane^j)*16): LDS slot l holds quad l^j (r17-verified).
    #pragma unroll
    for (int j = 0; j < 8; ++j) {
        const int R   = wid * 8 + j;        // 0..63
        const int tau = R >> 5, mr = R & 31;
        const float* src = ent + (size_t)(bs0 + tau) * 8192 + mr * 256 + ((lane ^ j) << 2);
        float* dst = &buf[tau * 8192 + mr * 256];
        __builtin_amdgcn_global_load_lds((const GLOBAL_AS void*)src,
                                         (LDS_AS void*)dst, 16, 0, 0);
    }

    // ---- B fragments for this wave's nj (register-resident) + scalars ----
    bf16x8 B[16];
    float ha = 0.f, wsa = 0.f;
    if (wid < NJ) {
        const bf16x8* wef8 = reinterpret_cast<const bf16x8*>(wef);
        #pragma unroll
        for (int kk = 0; kk < 16; ++kk) B[kk] = wef8[(wid * 16 + kk) * 64 + lane];
        const int a = wid * 32 + m;
        ha  = hattw[b * DAP + a];
        wsa = (a < DA) ? Ws[a] : 0.f;
    }

    __syncthreads();   // drains DMA + B loads -> buf ready

    // ---- MFMA both tiles (waves 0..6, one nj each, B in regs) ----
    if (wid < NJ) {
        const int sm = m & 7;
        #pragma unroll
        for (int tau = 0; tau < 2; ++tau) {
            const float4* bf4 = reinterpret_cast<const float4*>(&buf[tau * 8192]);
            f32x16 acc;
            #pragma unroll
            for (int q = 0; q < 16; ++q) acc[q] = 0.f;
            #pragma unroll
            for (int kk = 0; kk < 16; ++kk) {
                const int s0 = (kk * 4 + hi) ^ sm;      // low-half quad slot
                float4 p0 = bf4[m * 64 + s0];
                float4 p1 = bf4[m * 64 + (s0 ^ 2)];     // high-half quad
                bf16x8 fr = { (__bf16)p0.x, (__bf16)p0.y, (__bf16)p0.z, (__bf16)p0.w,
                              (__bf16)p1.x, (__bf16)p1.y, (__bf16)p1.z, (__bf16)p1.w };
                acc = __builtin_amdgcn_mfma_f32_32x32x16_bf16(fr, B[kk], acc, 0, 0, 0);
            }
            #pragma unroll
            for (int q = 0; q < 16; ++q) {
                float v = tanh_fast(acc[q] + ha) * wsa;
                v += __shfl_xor(v, 1);  v += __shfl_xor(v, 2);  v += __shfl_xor(v, 4);
                v += __shfl_xor(v, 8);  v += __shfl_xor(v, 16);
                if (m == 0)
                    partials[tau][wid][(q & 3) + 8 * (q >> 2) + 4 * hi] = v;
            }
        }
    }
    __syncthreads();   // partials ready

    // ---- epilogue: 256 threads per tile; softmax via shfl, wsum from LDS ----
    {
        const int tau = t >> 8;             // 0/1
        const int d   = t & 255;            // output col
        const int e0  = lane & 31;
        float lg = 0.f;
        #pragma unroll
        for (int w = 0; w < NJ; ++w) lg += partials[tau][w][e0];
        float mx = lg;
        mx = fmaxf(mx, __shfl_xor(mx, 1));  mx = fmaxf(mx, __shfl_xor(mx, 2));
        mx = fmaxf(mx, __shfl_xor(mx, 4));  mx = fmaxf(mx, __shfl_xor(mx, 8));
        mx = fmaxf(mx, __shfl_xor(mx, 16));
        float ex = __expf(lg - mx);
        float sm_ = ex;
        sm_ += __shfl_xor(sm_, 1);  sm_ += __shfl_xor(sm_, 2);  sm_ += __shfl_xor(sm_, 4);
        sm_ += __shfl_xor(sm_, 8);  sm_ += __shfl_xor(sm_, 16);
        const float wv = ex * __builtin_amdgcn_rcpf(sm_);

        const float* bt = &buf[tau * 8192];
        const int qd = d >> 2, ed = d & 3;
        float o = 0.f;
        #pragma unroll
        for (int e = 0; e < NE; ++e) {
            const float we = __shfl(wv, e);   // lanes 0..31 hold entity weights
            o = fmaf(we, bt[e * 256 + ((qd ^ (e & 7)) << 2) + ed], o);
        }
        out[(size_t)(bs0 + tau) * 256 + d] = o;
    }
}

extern "C" void kernel_launch(void* const* d_in, const int* in_sizes, int n_in,
                              void* d_out, int out_size, void* d_ws, size_t ws_size,
                              hipStream_t stream) {
    const float* cxt = (const float*)d_in[0];
    const float* ent = (const float*)d_in[1];
    const float* We  = (const float*)d_in[2];
    const float* Wh  = (const float*)d_in[3];
    const float* Ws  = (const float*)d_in[4];
    float* out = (float*)d_out;

    float*  psum  = (float*)d_ws;                       // 512*512 f32 = 1 MB
    float*  hattw = psum + 512 * DH;                    // 8*224 f32
    __bf16* wef   = (__bf16*)(hattw + NB * DAP);        // 7*16*512 bf16 = 112 KB

    hipLaunchKernelGGL(wef_build, dim3(NJ * 16), dim3(64), 0, stream, We, wef);
    hipLaunchKernelGGL(cmean_partial, dim3(512), dim3(256), 0, stream, cxt, psum);
    hipLaunchKernelGGL(hatt_from_psum, dim3(NB), dim3(256), 0, stream, psum, Wh, hattw);
    hipLaunchKernelGGL(entatt_main, dim3(2048), dim3(512), 0, stream,
                       ent, wef, hattw, Ws, out);
}